// Round 4
// baseline (90.340 us; speedup 1.0000x reference)
//
#include <hip/hip_runtime.h>

#define B_ 8
#define C_ 3
#define R_ 8
#define H_ 512
#define W_ 512
#define HW_ (H_*W_)
#define S_ 1024
#define CB_ 25
#define TB_ 10

// output offsets (floats)
#define O_AREA 0
#define O_BBOX 8192
#define O_COLOR 40960
#define O_TEX 655360
#define O_GRADS 2621440

// K1 block roles (hist first, conv last)
#define NTEX 768            // 192 planes x 4 chunks
#define NCOL 96             // 24 planes x 4 chunks
#define NBB  128            // 8 images x 16 chunks
#define NAREA 8
#define NHIST (NTEX + NCOL + NBB + NAREA)   // 1000
#define NCONV 512
#define NGRID1 (NHIST + NCONV)              // 1512

// scratch layout (u32 words): u16-packed partial hists
#define SC_TEX 0
#define SC_COL (NTEX * 5120)                 // 3,932,160
#define SC_B   (SC_COL + NCOL * 12800)       // 5,160,960
#define SCR_WORDS (SC_B + NBB * 2048)        // 5,423,104
#define NEED_WS ((size_t)SCR_WORDS * 4)      // 21,692,416 B

// K2 reduce work items
#define T_TEX (B_*C_*R_*S_*TB_)   // 1,966,080
#define T_COL (B_*C_*S_*CB_)      // 614,400
#define T_BB  (B_*S_)             // 8,192
#define NGRID2 ((T_TEX + T_COL + T_BB) / 1024)  // 2528 exact

__device__ __forceinline__ void conv_px(const float* __restrict__ img,
                                        float* __restrict__ out, int i) {
  const int pix = i & (HW_ - 1);
  const int bc = i >> 18;
  const int x = pix & (W_ - 1);
  const int y = pix >> 9;
  const float* im = img + (size_t)bc * HW_;
  const bool xm = x > 0, xp = x < W_ - 1, ym = y > 0, yp = y < H_ - 1;
  const float i00 = (ym && xm) ? im[pix - W_ - 1] : 0.f;
  const float i01 = ym ? im[pix - W_] : 0.f;
  const float i02 = (ym && xp) ? im[pix - W_ + 1] : 0.f;
  const float i10 = xm ? im[pix - 1] : 0.f;
  const float i12 = xp ? im[pix + 1] : 0.f;
  const float i20 = (yp && xm) ? im[pix + W_ - 1] : 0.f;
  const float i21 = yp ? im[pix + W_] : 0.f;
  const float i22 = (yp && xp) ? im[pix + W_ + 1] : 0.f;
  const float gx = 3.f*(i02 - i00) + 10.f*(i12 - i10) + 3.f*(i22 - i20);
  const float gy = 3.f*(i20 - i00) + 10.f*(i21 - i01) + 3.f*(i22 - i02);
  out[O_GRADS + (size_t)(bc*2 + 0)*HW_ + pix] = gx;
  out[O_GRADS + (size_t)(bc*2 + 1)*HW_ + pix] = gy;
}

// ================= K1: partial hists (+ area final, + upper conv) =================
__global__ __launch_bounds__(1024) void k_part(
    const float* __restrict__ img,
    const int* __restrict__ imgs_bins,
    const int* __restrict__ grads_bins,
    const int* __restrict__ lab,
    float* __restrict__ out,
    unsigned* __restrict__ scr,
    int pxsplit) {
  __shared__ unsigned smem[12800];   // 51.2 KB union
  const int bid = blockIdx.x;
  const int tid = threadIdx.x;

  if (bid < NTEX) {
    // ---- texture partial: plane = bid>>2, quarter image ----
    const int plane = bid >> 2, chunk = bid & 3;
    const int b = plane / (C_*R_);
    int* h = (int*)smem;                       // 10240 ints
    for (int i = tid; i < S_*TB_; i += 1024) h[i] = 0;
    __syncthreads();
    const int4* bp = (const int4*)(grads_bins + (size_t)plane*HW_) + chunk*16384;
    const int4* lp = (const int4*)(lab + (size_t)b*HW_) + chunk*16384;
    #pragma unroll 4
    for (int t = tid; t < 16384; t += 1024) {
      const int4 bn = bp[t];
      const int4 lv = lp[t];
      atomicAdd(&h[lv.x*TB_ + bn.x], 1);
      atomicAdd(&h[lv.y*TB_ + bn.y], 1);
      atomicAdd(&h[lv.z*TB_ + bn.z], 1);
      atomicAdd(&h[lv.w*TB_ + bn.w], 1);
    }
    __syncthreads();
    unsigned* dst = scr + SC_TEX + (size_t)bid * 5120;
    const int2* h2 = (const int2*)h;
    for (int i = tid; i < 5120; i += 1024) {
      const int2 v = h2[i];
      dst[i] = (unsigned)v.x | ((unsigned)v.y << 16);
    }
  } else if (bid < NTEX + NCOL) {
    // ---- color partial: u16-packed LDS, quarter image ----
    const int rid = bid - NTEX;
    const int plane = rid >> 2, chunk = rid & 3;
    const int b = plane / C_;
    unsigned* h = smem;                        // 12800 words
    for (int i = tid; i < 12800; i += 1024) h[i] = 0;
    __syncthreads();
    const int4* bp = (const int4*)(imgs_bins + (size_t)plane*HW_) + chunk*16384;
    const int4* lp = (const int4*)(lab + (size_t)b*HW_) + chunk*16384;
    #pragma unroll 4
    for (int t = tid; t < 16384; t += 1024) {
      const int4 bn = bp[t];
      const int4 lv = lp[t];
      const int j0 = lv.x*CB_ + bn.x;
      const int j1 = lv.y*CB_ + bn.y;
      const int j2 = lv.z*CB_ + bn.z;
      const int j3 = lv.w*CB_ + bn.w;
      atomicAdd(&h[j0 >> 1], 1u << ((j0 & 1) << 4));
      atomicAdd(&h[j1 >> 1], 1u << ((j1 & 1) << 4));
      atomicAdd(&h[j2 >> 1], 1u << ((j2 & 1) << 4));
      atomicAdd(&h[j3 >> 1], 1u << ((j3 & 1) << 4));
    }
    __syncthreads();
    unsigned* dst = scr + SC_COL + (size_t)rid * 12800;
    for (int i = tid; i < 12800; i += 1024) dst[i] = h[i];
  } else if (bid < NTEX + NCOL + NBB) {
    // ---- bbox partial: 1/16 image ----
    const int rid = bid - NTEX - NCOL;
    const int b = rid >> 4, chunk = rid & 15;
    int* mn = (int*)smem;   // xmin[1024], ymin[1024], xmax[1024], ymax[1024]
    for (int i = tid; i < 2048; i += 1024) mn[i] = 512;
    for (int i = tid; i < 2048; i += 1024) mn[2048 + i] = 0;
    __syncthreads();
    const int base = chunk * 16384;
    const int4* lp = (const int4*)(lab + (size_t)b*HW_) + chunk*4096;
    #pragma unroll 2
    for (int t = tid; t < 4096; t += 1024) {
      const int4 lv = lp[t];
      const int p = base + t*4;
      const int y = p >> 9;
      const int x = p & (W_ - 1);
      atomicMin(&mn[lv.x], x);       atomicMin(&mn[1024 + lv.x], y);
      atomicMax(&mn[2048 + lv.x], x);     atomicMax(&mn[3072 + lv.x], y);
      atomicMin(&mn[lv.y], x + 1);   atomicMin(&mn[1024 + lv.y], y);
      atomicMax(&mn[2048 + lv.y], x + 1); atomicMax(&mn[3072 + lv.y], y);
      atomicMin(&mn[lv.z], x + 2);   atomicMin(&mn[1024 + lv.z], y);
      atomicMax(&mn[2048 + lv.z], x + 2); atomicMax(&mn[3072 + lv.z], y);
      atomicMin(&mn[lv.w], x + 3);   atomicMin(&mn[1024 + lv.w], y);
      atomicMax(&mn[2048 + lv.w], x + 3); atomicMax(&mn[3072 + lv.w], y);
    }
    __syncthreads();
    unsigned* dst = scr + SC_B + (size_t)rid * 2048;
    dst[tid]        = (unsigned)mn[tid]        | ((unsigned)mn[1024 + tid] << 16);
    dst[1024 + tid] = (unsigned)mn[2048 + tid] | ((unsigned)mn[3072 + tid] << 16);
  } else if (bid < NHIST) {
    // ---- area: one block per image, full count, FINAL write ----
    const int b = bid - NTEX - NCOL - NBB;
    int* cnt = (int*)smem;
    cnt[tid] = 0;
    __syncthreads();
    const int4* lp = (const int4*)(lab + (size_t)b*HW_);
    #pragma unroll 4
    for (int t = tid; t < HW_/4; t += 1024) {
      const int4 lv = lp[t];
      atomicAdd(&cnt[lv.x], 1);
      atomicAdd(&cnt[lv.y], 1);
      atomicAdd(&cnt[lv.z], 1);
      atomicAdd(&cnt[lv.w], 1);
    }
    __syncthreads();
    out[O_AREA + b*S_ + tid] = (float)cnt[tid];
  } else {
    // ---- conv for px >= pxsplit (safe region above scratch watermark) ----
    const int cb = bid - NHIST;
    for (int i = pxsplit + cb*1024 + tid; i < B_*C_*HW_; i += NCONV*1024)
      conv_px(img, out, i);
  }
}

// ================= K2: reduce partials + normalize + bbox final =================
__global__ __launch_bounds__(1024) void k_reduce(float* __restrict__ out,
                                                 const unsigned* __restrict__ scr) {
  const int idx = blockIdx.x * 1024 + threadIdx.x;
  if (idx < T_TEX) {
    // output-contiguous: idx = b*245760 + l*240 + cr*10 + t
    const int b = idx / 245760;
    const int r1 = idx - b * 245760;
    const int l = r1 / 240;
    const int r2 = r1 - l * 240;
    const int cr = r2 / 10;
    const int t = r2 - cr * 10;
    const int j = l * TB_ + t;
    const unsigned sh = (j & 1) << 4;
    const unsigned* p = scr + SC_TEX + (size_t)(b*(C_*R_) + cr) * 4 * 5120 + (j >> 1);
    const unsigned s = ((p[0] >> sh) & 0xFFFFu) + ((p[5120] >> sh) & 0xFFFFu)
                     + ((p[2*5120] >> sh) & 0xFFFFu) + ((p[3*5120] >> sh) & 0xFFFFu);
    const float a = out[O_AREA + b*S_ + l];
    out[O_TEX + idx] = (float)s / (a * 24.0f + 1e-12f);
  } else if (idx < T_TEX + T_COL) {
    // idx = b*76800 + l*75 + c*25 + ci
    const int o = idx - T_TEX;
    const int b = o / 76800;
    const int r1 = o - b * 76800;
    const int l = r1 / 75;
    const int r2 = r1 - l * 75;
    const int c = r2 / 25;
    const int ci = r2 - c * 25;
    const int j = l * CB_ + ci;
    const unsigned sh = (j & 1) << 4;
    const unsigned* p = scr + SC_COL + (size_t)(b*C_ + c) * 4 * 12800 + (j >> 1);
    const unsigned s = ((p[0] >> sh) & 0xFFFFu) + ((p[12800] >> sh) & 0xFFFFu)
                     + ((p[2*12800] >> sh) & 0xFFFFu) + ((p[3*12800] >> sh) & 0xFFFFu);
    const float a = out[O_AREA + b*S_ + l];
    out[O_COLOR + o] = (float)s / (a * 3.0f + 1e-12f);
  } else {
    const int i = idx - T_TEX - T_COL;   // 0..8191
    const int b = i >> 10, l = i & (S_ - 1);
    int xmn = W_, ymn = H_, xmx = 0, ymx = 0;
    const unsigned* p = scr + SC_B + (size_t)(b*16) * 2048 + l;
    #pragma unroll
    for (int k = 0; k < 16; ++k) {
      const unsigned w0 = p[k*2048];
      const unsigned w1 = p[k*2048 + 1024];
      xmn = min(xmn, (int)(w0 & 0xFFFFu)); ymn = min(ymn, (int)(w0 >> 16));
      xmx = max(xmx, (int)(w1 & 0xFFFFu)); ymx = max(ymx, (int)(w1 >> 16));
    }
    float4 v;
    v.x = (float)xmn; v.y = (float)ymn;
    v.z = (float)(xmx - xmn); v.w = (float)(ymx - ymn);
    ((float4*)(out + O_BBOX))[i] = v;
  }
}

// ================= K3: conv for px < pxsplit (after scratch consumed) =================
__global__ __launch_bounds__(1024) void k_conv_lo(const float* __restrict__ img,
                                                  float* __restrict__ out, int pxsplit) {
  for (int i = blockIdx.x*1024 + threadIdx.x; i < pxsplit; i += NCONV*1024)
    conv_px(img, out, i);
}

extern "C" void kernel_launch(void* const* d_in, const int* in_sizes, int n_in,
                              void* d_out, int out_size, void* d_ws, size_t ws_size,
                              hipStream_t stream) {
  const float* img = (const float*)d_in[0];
  const int* imgs_bins = (const int*)d_in[1];
  const int* grads_bins = (const int*)d_in[2];
  const int* reg_lab = (const int*)d_in[3];
  float* out = (float*)d_out;

  const bool ws_ok = ws_size >= NEED_WS;
  unsigned* scr = ws_ok ? (unsigned*)d_ws : (unsigned*)(out + O_GRADS);
  // with in-output scratch, K1's conv must stay above the scratch watermark:
  // scratch = 5,423,104 floats; first safe plane pair is bc=11 (11*2*HW = 5,767,168)
  const int pxsplit = ws_ok ? 0 : 11 * HW_;

  hipLaunchKernelGGL(k_part, dim3(NGRID1), dim3(1024), 0, stream,
                     img, imgs_bins, grads_bins, reg_lab, out, scr, pxsplit);
  hipLaunchKernelGGL(k_reduce, dim3(NGRID2), dim3(1024), 0, stream, out, scr);
  if (!ws_ok) {
    hipLaunchKernelGGL(k_conv_lo, dim3(NCONV), dim3(1024), 0, stream,
                       img, out, pxsplit);
  }
}

// Round 5
// 87.037 us; speedup vs baseline: 1.0379x; 1.0379x over previous
//
#include <hip/hip_runtime.h>

#define B_ 8
#define C_ 3
#define R_ 8
#define H_ 512
#define W_ 512
#define HW_ (H_*W_)
#define S_ 1024
#define CB_ 25
#define TB_ 10

// output offsets (floats)
#define O_AREA 0
#define O_BBOX 8192
#define O_COLOR 40960
#define O_TEX 655360
#define O_GRADS 2621440

// K1 block roles (fat blocks first)
#define NTEX (B_*C_*R_)              // 192 full-plane tex blocks
#define NCOL (B_*C_)                 // 24 full-plane color blocks
#define NBBC (B_*16)                 // 128 bbox chunk blocks
#define NHIST (NTEX + NCOL + NBBC)   // 344
#define NCONV 1024
#define NGRID (NHIST + NCONV)        // 1368

// ---------------- K0: init bbox slots as ints {512,512,0,0} ----------------
__global__ __launch_bounds__(1024) void k_init_bbox(float* __restrict__ out) {
  const int i = blockIdx.x * 1024 + threadIdx.x;
  if (i < B_*S_) {
    int4* p = (int4*)(out + O_BBOX);
    p[i] = make_int4(W_, H_, 0, 0);
  }
}

// ---------------- K1: fused hist + bbox partial + conv ----------------
__global__ __launch_bounds__(1024) void k_fused(
    const float* __restrict__ img,
    const int* __restrict__ imgs_bins,
    const int* __restrict__ grads_bins,
    const int* __restrict__ lab,
    float* __restrict__ out) {
  __shared__ unsigned smem[12800];   // 51.2 KB union
  const int bid = blockIdx.x;
  const int tid = threadIdx.x;

  if (bid < NTEX) {
    // ---- texture hist plane (b, cr): full image, exclusive final write ----
    const int plane = bid;                  // b*24 + cr
    const int b = plane / (C_*R_);
    const int cr = plane - b * (C_*R_);
    int* h = (int*)smem;                    // S*TB = 10240 ints (40 KB)
    for (int i = tid; i < S_*TB_; i += 1024) h[i] = 0;
    __syncthreads();
    const int4* bp = (const int4*)(grads_bins + (size_t)plane * HW_);
    const int4* lp = (const int4*)(lab + (size_t)b * HW_);
    for (int t = tid; t < HW_/4; t += 1024) {
      const int4 bn = bp[t];
      const int4 lv = lp[t];
      atomicAdd(&h[lv.x*TB_ + bn.x], 1);
      atomicAdd(&h[lv.y*TB_ + bn.y], 1);
      atomicAdd(&h[lv.z*TB_ + bn.z], 1);
      atomicAdd(&h[lv.w*TB_ + bn.w], 1);
    }
    __syncthreads();
    // thread l: area = sum of its 10 bins -> normalize + write
    {
      const int base = tid * TB_;
      int s = 0;
      #pragma unroll
      for (int t = 0; t < TB_; ++t) s += h[base + t];
      const float inv = 1.0f / ((float)s * 24.0f + 1e-12f);
      float* o = out + O_TEX + (size_t)b * (S_ * C_*R_*TB_) + tid * (C_*R_*TB_) + cr * TB_;
      #pragma unroll
      for (int t = 0; t < TB_; ++t) o[t] = (float)h[base + t] * inv;
      if (cr == 0) out[O_AREA + b * S_ + tid] = (float)s;
    }
  } else if (bid < NTEX + NCOL) {
    // ---- color hist plane (b,c): u16-packed LDS, exclusive final write ----
    const int plane = bid - NTEX;           // b*3 + c
    const int b = plane / C_;
    const int c = plane - b * C_;
    unsigned* h = smem;                     // 12800 words (51.2 KB)
    for (int i = tid; i < (S_*CB_)/2; i += 1024) h[i] = 0;
    __syncthreads();
    const int4* bp = (const int4*)(imgs_bins + (size_t)plane * HW_);
    const int4* lp = (const int4*)(lab + (size_t)b * HW_);
    for (int t = tid; t < HW_/4; t += 1024) {
      const int4 bn = bp[t];
      const int4 lv = lp[t];
      const int j0 = lv.x*CB_ + bn.x;
      const int j1 = lv.y*CB_ + bn.y;
      const int j2 = lv.z*CB_ + bn.z;
      const int j3 = lv.w*CB_ + bn.w;
      atomicAdd(&h[j0 >> 1], 1u << ((j0 & 1) << 4));
      atomicAdd(&h[j1 >> 1], 1u << ((j1 & 1) << 4));
      atomicAdd(&h[j2 >> 1], 1u << ((j2 & 1) << 4));
      atomicAdd(&h[j3 >> 1], 1u << ((j3 & 1) << 4));
    }
    __syncthreads();
    {
      int s = 0;
      #pragma unroll
      for (int ci = 0; ci < CB_; ++ci) {
        const int j = tid * CB_ + ci;
        s += (int)((h[j >> 1] >> ((j & 1) << 4)) & 0xFFFFu);
      }
      const float inv = 1.0f / ((float)s * 3.0f + 1e-12f);
      float* o = out + O_COLOR + (size_t)b * (S_ * C_*CB_) + tid * (C_*CB_) + c * CB_;
      #pragma unroll
      for (int ci = 0; ci < CB_; ++ci) {
        const int j = tid * CB_ + ci;
        o[ci] = (float)((h[j >> 1] >> ((j & 1) << 4)) & 0xFFFFu) * inv;
      }
    }
  } else if (bid < NHIST) {
    // ---- bbox chunk (b, 1/16 image): LDS partial -> global int atomics ----
    const int rid = bid - NTEX - NCOL;
    const int b = rid >> 4, chunk = rid & 15;
    int* mn = (int*)smem;   // xmin[1024], ymin[1024], xmax[1024], ymax[1024]
    mn[tid] = W_; mn[1024 + tid] = H_; mn[2048 + tid] = 0; mn[3072 + tid] = 0;
    __syncthreads();
    const int base = chunk * 16384;
    const int4* lp = (const int4*)(lab + (size_t)b * HW_) + chunk * 4096;
    #pragma unroll 2
    for (int t = tid; t < 4096; t += 1024) {
      const int4 lv = lp[t];
      const int p = base + t * 4;
      const int y = p >> 9;
      const int x = p & (W_ - 1);   // 4-aligned, same row
      atomicMin(&mn[lv.x], x);       atomicMin(&mn[1024 + lv.x], y);
      atomicMax(&mn[2048 + lv.x], x);     atomicMax(&mn[3072 + lv.x], y);
      atomicMin(&mn[lv.y], x + 1);   atomicMin(&mn[1024 + lv.y], y);
      atomicMax(&mn[2048 + lv.y], x + 1); atomicMax(&mn[3072 + lv.y], y);
      atomicMin(&mn[lv.z], x + 2);   atomicMin(&mn[1024 + lv.z], y);
      atomicMax(&mn[2048 + lv.z], x + 2); atomicMax(&mn[3072 + lv.z], y);
      atomicMin(&mn[lv.w], x + 3);   atomicMin(&mn[1024 + lv.w], y);
      atomicMax(&mn[2048 + lv.w], x + 3); atomicMax(&mn[3072 + lv.w], y);
    }
    __syncthreads();
    // thread l merges label l into the global int slots (order-independent)
    {
      int* gb = (int*)(out + O_BBOX) + (size_t)(b * S_ + tid) * 4;
      atomicMin(&gb[0], mn[tid]);
      atomicMin(&gb[1], mn[1024 + tid]);
      atomicMax(&gb[2], mn[2048 + tid]);
      atomicMax(&gb[3], mn[3072 + tid]);
    }
  } else {
    // ---- Scharr gradients, grid-stride ----
    const int cb = bid - NHIST;
    const int tot = B_*C_*HW_;
    for (int i = cb * 1024 + tid; i < tot; i += NCONV * 1024) {
      const int pix = i & (HW_ - 1);
      const int bc = i >> 18;
      const int x = pix & (W_ - 1);
      const int y = pix >> 9;
      const float* im = img + (size_t)bc * HW_;
      const bool xm = x > 0, xp = x < W_ - 1, ym = y > 0, yp = y < H_ - 1;
      const float i00 = (ym && xm) ? im[pix - W_ - 1] : 0.f;
      const float i01 = ym ? im[pix - W_] : 0.f;
      const float i02 = (ym && xp) ? im[pix - W_ + 1] : 0.f;
      const float i10 = xm ? im[pix - 1] : 0.f;
      const float i12 = xp ? im[pix + 1] : 0.f;
      const float i20 = (yp && xm) ? im[pix + W_ - 1] : 0.f;
      const float i21 = yp ? im[pix + W_] : 0.f;
      const float i22 = (yp && xp) ? im[pix + W_ + 1] : 0.f;
      const float gx = 3.f*(i02 - i00) + 10.f*(i12 - i10) + 3.f*(i22 - i20);
      const float gy = 3.f*(i20 - i00) + 10.f*(i21 - i01) + 3.f*(i22 - i02);
      out[O_GRADS + (size_t)(bc*2 + 0)*HW_ + pix] = gx;
      out[O_GRADS + (size_t)(bc*2 + 1)*HW_ + pix] = gy;
    }
  }
}

// ---------------- K2: bbox int -> float, w/h ----------------
__global__ __launch_bounds__(1024) void k_fin_bbox(float* __restrict__ out) {
  const int i = blockIdx.x * 1024 + threadIdx.x;
  if (i < B_*S_) {
    const int4 v = ((const int4*)(out + O_BBOX))[i];
    float4 f;
    f.x = (float)v.x; f.y = (float)v.y;
    f.z = (float)(v.z - v.x); f.w = (float)(v.w - v.y);
    ((float4*)(out + O_BBOX))[i] = f;
  }
}

extern "C" void kernel_launch(void* const* d_in, const int* in_sizes, int n_in,
                              void* d_out, int out_size, void* d_ws, size_t ws_size,
                              hipStream_t stream) {
  const float* img = (const float*)d_in[0];
  const int* imgs_bins = (const int*)d_in[1];
  const int* grads_bins = (const int*)d_in[2];
  const int* reg_lab = (const int*)d_in[3];
  float* out = (float*)d_out;

  hipLaunchKernelGGL(k_init_bbox, dim3(8), dim3(1024), 0, stream, out);
  hipLaunchKernelGGL(k_fused, dim3(NGRID), dim3(1024), 0, stream,
                     img, imgs_bins, grads_bins, reg_lab, out);
  hipLaunchKernelGGL(k_fin_bbox, dim3(8), dim3(1024), 0, stream, out);
}

// Round 6
// 85.026 us; speedup vs baseline: 1.0625x; 1.0237x over previous
//
#include <hip/hip_runtime.h>

#define B_ 8
#define C_ 3
#define R_ 8
#define H_ 512
#define W_ 512
#define HW_ (H_*W_)
#define S_ 1024
#define CB_ 25
#define TB_ 10

// output offsets (floats)
#define O_AREA 0
#define O_BBOX 8192
#define O_COLOR 40960
#define O_TEX 655360
#define O_GRADS 2621440

// K1 block roles: tex 0..383, col 384..431, bbox 432..559, conv 560..
#define NTEXU 384               // 192 planes x 2 half-plane chunks
#define NCOLU 48                // 24 planes x 2
#define NBBU  128               // 8 images x 16
#define NHIST (NTEXU + NCOLU + NBBU)   // 560
#define NCONV 1024
#define NGRID1 (NHIST + NCONV)

// scratch (u32 words), u16-packed partial hists
#define SC_TEX 0
#define SC_COL (NTEXU * 5120)                 // 1,966,080
#define SC_B   (SC_COL + NCOLU * 12800)       // 2,580,480
#define SCR_WORDS (SC_B + NBBU * 2048)        // 2,842,624
#define NEED_WS ((size_t)SCR_WORDS * 4)       // 11,370,496 B
#define BCSKIP 6   // fallback: scratch overlays grads planes bc<6 (3,145,728 floats)

__device__ __forceinline__ void conv_px(const float* __restrict__ img,
                                        float* __restrict__ out, int i) {
  const int pix = i & (HW_ - 1);
  const int bc = i >> 18;
  const int x = pix & (W_ - 1);
  const int y = pix >> 9;
  const float* im = img + (size_t)bc * HW_;
  const bool xm = x > 0, xp = x < W_ - 1, ym = y > 0, yp = y < H_ - 1;
  const float i00 = (ym && xm) ? im[pix - W_ - 1] : 0.f;
  const float i01 = ym ? im[pix - W_] : 0.f;
  const float i02 = (ym && xp) ? im[pix - W_ + 1] : 0.f;
  const float i10 = xm ? im[pix - 1] : 0.f;
  const float i12 = xp ? im[pix + 1] : 0.f;
  const float i20 = (yp && xm) ? im[pix + W_ - 1] : 0.f;
  const float i21 = yp ? im[pix + W_] : 0.f;
  const float i22 = (yp && xp) ? im[pix + W_ + 1] : 0.f;
  const float gx = 3.f*(i02 - i00) + 10.f*(i12 - i10) + 3.f*(i22 - i20);
  const float gy = 3.f*(i20 - i00) + 10.f*(i21 - i01) + 3.f*(i22 - i02);
  out[O_GRADS + (size_t)(bc*2 + 0)*HW_ + pix] = gx;
  out[O_GRADS + (size_t)(bc*2 + 1)*HW_ + pix] = gy;
}

// ============ K1: latency-batched hist partials + conv ============
__global__ __launch_bounds__(1024, 8) void k_part(
    const float* __restrict__ img,
    const int* __restrict__ imgs_bins,
    const int* __restrict__ grads_bins,
    const int* __restrict__ lab,
    float* __restrict__ out,
    unsigned* __restrict__ scr,
    int convlo) {            // first bc handled by K1's conv blocks
  __shared__ unsigned smem[12800];   // 51.2 KB union
  const int bid = blockIdx.x;
  const int tid = threadIdx.x;

  if (bid < NTEXU) {
    // ---- tex half-plane: u16-packed LDS hist (5120 words) ----
    const int plane = bid >> 1, chunk = bid & 1;   // plane = b*24 + cr
    const int b = plane / (C_*R_);
    for (int i = tid; i < 5120; i += 1024) smem[i] = 0;
    __syncthreads();
    const int4* bp = (const int4*)(grads_bins + (size_t)plane*HW_) + chunk*32768;
    const int4* lp = (const int4*)(lab + (size_t)b*HW_) + chunk*32768;
    #pragma unroll 1
    for (int it = 0; it < 8; ++it) {
      const int i = it*4096 + tid;
      // 8 independent loads issue before any use -> 4x latency hiding
      const int4 b0 = bp[i], b1 = bp[i+1024], b2 = bp[i+2048], b3 = bp[i+3072];
      const int4 l0 = lp[i], l1 = lp[i+1024], l2 = lp[i+2048], l3 = lp[i+3072];
      #define TEX1(L,Bv) { const int j = (L)*TB_ + (Bv); \
        atomicAdd(&smem[j >> 1], 1u << ((j & 1) << 4)); }
      TEX1(l0.x,b0.x) TEX1(l0.y,b0.y) TEX1(l0.z,b0.z) TEX1(l0.w,b0.w)
      TEX1(l1.x,b1.x) TEX1(l1.y,b1.y) TEX1(l1.z,b1.z) TEX1(l1.w,b1.w)
      TEX1(l2.x,b2.x) TEX1(l2.y,b2.y) TEX1(l2.z,b2.z) TEX1(l2.w,b2.w)
      TEX1(l3.x,b3.x) TEX1(l3.y,b3.y) TEX1(l3.z,b3.z) TEX1(l3.w,b3.w)
      #undef TEX1
    }
    __syncthreads();
    unsigned* dst = scr + SC_TEX + (size_t)bid * 5120;
    for (int i = tid; i < 5120; i += 1024) dst[i] = smem[i];
  } else if (bid < NTEXU + NCOLU) {
    // ---- col half-plane: u16-packed LDS hist (12800 words) ----
    const int rid = bid - NTEXU;
    const int plane = rid >> 1, chunk = rid & 1;   // plane = b*3 + c
    const int b = plane / C_;
    for (int i = tid; i < 12800; i += 1024) smem[i] = 0;
    __syncthreads();
    const int4* bp = (const int4*)(imgs_bins + (size_t)plane*HW_) + chunk*32768;
    const int4* lp = (const int4*)(lab + (size_t)b*HW_) + chunk*32768;
    #pragma unroll 1
    for (int it = 0; it < 8; ++it) {
      const int i = it*4096 + tid;
      const int4 b0 = bp[i], b1 = bp[i+1024], b2 = bp[i+2048], b3 = bp[i+3072];
      const int4 l0 = lp[i], l1 = lp[i+1024], l2 = lp[i+2048], l3 = lp[i+3072];
      #define COL1(L,Bv) { const int j = (L)*CB_ + (Bv); \
        atomicAdd(&smem[j >> 1], 1u << ((j & 1) << 4)); }
      COL1(l0.x,b0.x) COL1(l0.y,b0.y) COL1(l0.z,b0.z) COL1(l0.w,b0.w)
      COL1(l1.x,b1.x) COL1(l1.y,b1.y) COL1(l1.z,b1.z) COL1(l1.w,b1.w)
      COL1(l2.x,b2.x) COL1(l2.y,b2.y) COL1(l2.z,b2.z) COL1(l2.w,b2.w)
      COL1(l3.x,b3.x) COL1(l3.y,b3.y) COL1(l3.z,b3.z) COL1(l3.w,b3.w)
      #undef COL1
    }
    __syncthreads();
    unsigned* dst = scr + SC_COL + (size_t)rid * 12800;
    for (int i = tid; i < 12800; i += 1024) dst[i] = smem[i];
  } else if (bid < NHIST) {
    // ---- bbox 1/16-image chunk ----
    const int rid = bid - NTEXU - NCOLU;
    const int b = rid >> 4, chunk = rid & 15;
    int* mn = (int*)smem;
    mn[tid] = W_; mn[1024+tid] = H_; mn[2048+tid] = 0; mn[3072+tid] = 0;
    __syncthreads();
    const int4* lp = (const int4*)(lab + (size_t)b*HW_) + chunk*4096;
    {
      const int i = tid;
      const int4 l0 = lp[i], l1 = lp[i+1024], l2 = lp[i+2048], l3 = lp[i+3072];
      #define BB1(L,P) { const int y = (P) >> 9, x = (P) & (W_-1); \
        atomicMin(&mn[L], x); atomicMin(&mn[1024+(L)], y); \
        atomicMax(&mn[2048+(L)], x); atomicMax(&mn[3072+(L)], y); }
      const int p0 = (chunk*4096 + tid) * 4;
      BB1(l0.x, p0) BB1(l0.y, p0+1) BB1(l0.z, p0+2) BB1(l0.w, p0+3)
      const int p1 = (chunk*4096 + 1024 + tid) * 4;
      BB1(l1.x, p1) BB1(l1.y, p1+1) BB1(l1.z, p1+2) BB1(l1.w, p1+3)
      const int p2 = (chunk*4096 + 2048 + tid) * 4;
      BB1(l2.x, p2) BB1(l2.y, p2+1) BB1(l2.z, p2+2) BB1(l2.w, p2+3)
      const int p3 = (chunk*4096 + 3072 + tid) * 4;
      BB1(l3.x, p3) BB1(l3.y, p3+1) BB1(l3.z, p3+2) BB1(l3.w, p3+3)
      #undef BB1
    }
    __syncthreads();
    unsigned* dst = scr + SC_B + (size_t)rid * 2048;
    dst[tid]      = (unsigned)mn[tid]      | ((unsigned)mn[1024+tid] << 16);
    dst[1024+tid] = (unsigned)mn[2048+tid] | ((unsigned)mn[3072+tid] << 16);
  } else {
    // ---- conv, bc >= convlo ----
    const int cb = bid - NHIST;
    const int lo = convlo << 18;
    for (int i = lo + cb*1024 + tid; i < (B_*C_) << 18; i += NCONV*1024)
      conv_px(img, out, i);
  }
}

// ============ K2: fused reduce (area, tex, col, bbox) ============
__global__ __launch_bounds__(1024) void k_reduce(float* __restrict__ out,
                                                 const unsigned* __restrict__ scr) {
  __shared__ float aInv24[64], aInv3[64];
  const int m = blockIdx.x;           // 128 blocks: (b, 64-label tile)
  const int b = m >> 4, l0 = (m & 15) * 64;
  const int tid = threadIdx.x;
  // area from tex cr=0 partials: words l*5 .. l*5+4 in both chunks
  if (tid < 64) {
    const int l = l0 + tid;
    const unsigned* p0 = scr + SC_TEX + (size_t)(b*24*2 + 0)*5120 + l*5;
    const unsigned* p1 = scr + SC_TEX + (size_t)(b*24*2 + 1)*5120 + l*5;
    int s = 0;
    #pragma unroll
    for (int w = 0; w < 5; ++w) {
      const unsigned a = p0[w], c = p1[w];
      s += (int)(a & 0xFFFFu) + (int)(a >> 16) + (int)(c & 0xFFFFu) + (int)(c >> 16);
    }
    out[O_AREA + b*S_ + l] = (float)s;
    aInv24[tid] = 1.0f / ((float)s * 24.0f + 1e-12f);
    aInv3[tid]  = 1.0f / ((float)s * 3.0f + 1e-12f);
  }
  __syncthreads();
  // tex: 64 labels x 240
  for (int k = tid; k < 64*240; k += 1024) {
    const int dl = k / 240, rem = k - dl*240;
    const int cr = rem / 10, t = rem - cr*10;
    const int l = l0 + dl;
    const int j = l*TB_ + t;
    const unsigned sh = (j & 1) << 4;
    const unsigned* p = scr + SC_TEX + (size_t)((b*24 + cr)*2)*5120 + (j >> 1);
    const unsigned s = ((p[0] >> sh) & 0xFFFFu) + ((p[5120] >> sh) & 0xFFFFu);
    out[O_TEX + (size_t)b*245760 + l*240 + rem] = (float)s * aInv24[dl];
  }
  // col: 64 labels x 75
  for (int k = tid; k < 64*75; k += 1024) {
    const int dl = k / 75, rem = k - dl*75;
    const int c = rem / 25, ci = rem - c*25;
    const int l = l0 + dl;
    const int j = l*CB_ + ci;
    const unsigned sh = (j & 1) << 4;
    const unsigned* p = scr + SC_COL + (size_t)((b*3 + c)*2)*12800 + (j >> 1);
    const unsigned s = ((p[0] >> sh) & 0xFFFFu) + ((p[12800] >> sh) & 0xFFFFu);
    out[O_COLOR + (size_t)b*76800 + l*75 + rem] = (float)s * aInv3[dl];
  }
  // bbox: 64 labels x 16 chunks
  if (tid < 64) {
    const int l = l0 + tid;
    int xmn = W_, ymn = H_, xmx = 0, ymx = 0;
    const unsigned* p = scr + SC_B + (size_t)(b*16)*2048 + l;
    #pragma unroll
    for (int k = 0; k < 16; ++k) {
      const unsigned w0 = p[k*2048];
      const unsigned w1 = p[k*2048 + 1024];
      xmn = min(xmn, (int)(w0 & 0xFFFFu)); ymn = min(ymn, (int)(w0 >> 16));
      xmx = max(xmx, (int)(w1 & 0xFFFFu)); ymx = max(ymx, (int)(w1 >> 16));
    }
    float4 v;
    v.x = (float)xmn; v.y = (float)ymn;
    v.z = (float)(xmx - xmn); v.w = (float)(ymx - ymn);
    ((float4*)(out + O_BBOX))[b*S_ + l] = v;
  }
}

// ============ K3 (fallback only): conv bc < BCSKIP ============
__global__ __launch_bounds__(1024) void k_conv_lo(const float* __restrict__ img,
                                                  float* __restrict__ out) {
  const int i = blockIdx.x*1024 + threadIdx.x;   // grid covers BCSKIP<<18 exactly
  conv_px(img, out, i);
}

extern "C" void kernel_launch(void* const* d_in, const int* in_sizes, int n_in,
                              void* d_out, int out_size, void* d_ws, size_t ws_size,
                              hipStream_t stream) {
  const float* img = (const float*)d_in[0];
  const int* imgs_bins = (const int*)d_in[1];
  const int* grads_bins = (const int*)d_in[2];
  const int* reg_lab = (const int*)d_in[3];
  float* out = (float*)d_out;

  const bool ws_ok = ws_size >= NEED_WS;
  unsigned* scr = ws_ok ? (unsigned*)d_ws : (unsigned*)(out + O_GRADS);
  const int convlo = ws_ok ? 0 : BCSKIP;

  hipLaunchKernelGGL(k_part, dim3(NGRID1), dim3(1024), 0, stream,
                     img, imgs_bins, grads_bins, reg_lab, out, scr, convlo);
  hipLaunchKernelGGL(k_reduce, dim3(128), dim3(1024), 0, stream, out, scr);
  if (!ws_ok) {
    hipLaunchKernelGGL(k_conv_lo, dim3((BCSKIP << 18) / 1024), dim3(1024), 0, stream,
                       img, out);
  }
}